// Round 6
// baseline (135.292 us; speedup 1.0000x reference)
//
#include <hip/hip_runtime.h>
#include <math.h>

// Batched 3x3 polar decomposition, wave-autonomous:
//  - each wave stages its own 128 matrices global->LDS via global_load_lds
//    (linear dest, 4x16B + 2x4B per lane), NO __syncthreads anywhere
//  - 2 matrices/thread packed into float2 vectors -> v_pk_fma_f32
//  - 6 det-scaled Newton iterations + 2 Newton-Schulz polish
//  - results stored DIRECTLY from registers (nontemporal, stride-72B per
//    lane; L2 write-merging keeps HBM volume exact) -- no output LDS
//    restage, no lgkmcnt drains on the store path.

typedef float v2f __attribute__((ext_vector_type(2)));
typedef float v4f __attribute__((ext_vector_type(4)));
typedef v4f v4fa8 __attribute__((aligned(8)));   // 16B vector, 8B-aligned slots
typedef v2f v2fa8 __attribute__((aligned(8)));

#define NEWTON_ITERS 6
#define NS_ITERS 2

__device__ __forceinline__ void polar_pair(
    v2f& x00, v2f& x01, v2f& x02,
    v2f& x10, v2f& x11, v2f& x12,
    v2f& x20, v2f& x21, v2f& x22)
{
    #pragma unroll
    for (int it = 0; it < NEWTON_ITERS; ++it) {
        v2f c00 = x11*x22 - x12*x21;
        v2f c01 = x12*x20 - x10*x22;
        v2f c02 = x10*x21 - x11*x20;
        v2f c10 = x02*x21 - x01*x22;
        v2f c11 = x00*x22 - x02*x20;
        v2f c12 = x01*x20 - x00*x21;
        v2f c20 = x01*x12 - x02*x11;
        v2f c21 = x02*x10 - x00*x12;
        v2f c22 = x00*x11 - x01*x10;

        v2f det = x00*c00 + x01*c01 + x02*c02;

        float d0 = det.x, d1 = det.y;
        float ad0 = fmaxf(fabsf(d0), 1e-30f);
        float ad1 = fmaxf(fabsf(d1), 1e-30f);
        float z0 = __builtin_amdgcn_exp2f(__builtin_amdgcn_logf(ad0) * (-1.0f/3.0f));
        float z1 = __builtin_amdgcn_exp2f(__builtin_amdgcn_logf(ad1) * (-1.0f/3.0f));
        v2f s = {0.5f * z0, 0.5f * z1};
        v2f u = {copysignf(0.5f * z0 * z0, d0), copysignf(0.5f * z1 * z1, d1)};

        x00 = s*x00 + u*c00;  x01 = s*x01 + u*c01;  x02 = s*x02 + u*c02;
        x10 = s*x10 + u*c10;  x11 = s*x11 + u*c11;  x12 = s*x12 + u*c12;
        x20 = s*x20 + u*c20;  x21 = s*x21 + u*c21;  x22 = s*x22 + u*c22;
    }

    #pragma unroll
    for (int it = 0; it < NS_ITERS; ++it) {
        v2f s00 = x00*x00 + x10*x10 + x20*x20;
        v2f s01 = x00*x01 + x10*x11 + x20*x21;
        v2f s02 = x00*x02 + x10*x12 + x20*x22;
        v2f s11 = x01*x01 + x11*x11 + x21*x21;
        v2f s12 = x01*x02 + x11*x12 + x21*x22;
        v2f s22 = x02*x02 + x12*x12 + x22*x22;
        v2f t00 = 1.5f - 0.5f*s00, t01 = -0.5f*s01, t02 = -0.5f*s02;
        v2f t11 = 1.5f - 0.5f*s11, t12 = -0.5f*s12;
        v2f t22 = 1.5f - 0.5f*s22;
        v2f y00 = x00*t00 + x01*t01 + x02*t02;
        v2f y01 = x00*t01 + x01*t11 + x02*t12;
        v2f y02 = x00*t02 + x01*t12 + x02*t22;
        v2f y10 = x10*t00 + x11*t01 + x12*t02;
        v2f y11 = x10*t01 + x11*t11 + x12*t12;
        v2f y12 = x10*t02 + x11*t12 + x12*t22;
        v2f y20 = x20*t00 + x21*t01 + x22*t02;
        v2f y21 = x20*t01 + x21*t11 + x22*t12;
        v2f y22 = x20*t02 + x21*t12 + x22*t22;
        x00=y00; x01=y01; x02=y02;
        x10=y10; x11=y11; x12=y12;
        x20=y20; x21=y21; x22=y22;
    }
}

__global__ __launch_bounds__(256) void polar3x3_wave_kernel(
    const float* __restrict__ rot,   // [n,3,3]
    const float* __restrict__ mat,   // [3,3] broadcast
    float* __restrict__ out,         // [n,3,3] then logdet[n]
    int n)
{
    __shared__ float lds[4608];              // 4 waves * 1152 floats (input only)
    const int t    = threadIdx.x;
    const int lane = t & 63;
    const int w    = t >> 6;
    const long long blockBase = (long long)blockIdx.x * 512;  // matrices
    const long long waveBase  = blockBase + (long long)w * 128;
    float* wlds = lds + w * 1152;

    // uniform parameter (scalar loads, overlap with staging)
    const float m00 = mat[0], m01 = mat[1], m02 = mat[2];
    const float m10 = mat[3], m11 = mat[4], m12 = mat[5];
    const float m20 = mat[6], m21 = mat[7], m22 = mat[8];

    const bool full = (blockBase + 512 <= (long long)n);

    v2f r00, r01, r02, r10, r11, r12, r20, r21, r22;

    if (full) {
        // ---- wave-local staging: 1152 floats, linear, no barrier ----
        const float* gsrc = rot + waveBase * 9;
        #pragma unroll
        for (int k = 0; k < 4; ++k) {
            __builtin_amdgcn_global_load_lds(
                (const __attribute__((address_space(1))) void*)(gsrc + k * 256 + lane * 4),
                (__attribute__((address_space(3))) void*)(wlds + k * 256),
                16, 0, 0);
        }
        #pragma unroll
        for (int k = 0; k < 2; ++k) {
            __builtin_amdgcn_global_load_lds(
                (const __attribute__((address_space(1))) void*)(gsrc + 1024 + k * 64 + lane),
                (__attribute__((address_space(3))) void*)(wlds + 1024 + k * 64),
                4, 0, 0);
        }
        asm volatile("s_waitcnt vmcnt(0)" ::: "memory");

        const float* L = wlds + lane * 18;   // this lane's 2 matrices
        r00 = v2f{L[0], L[9]};  r01 = v2f{L[1], L[10]}; r02 = v2f{L[2], L[11]};
        r10 = v2f{L[3], L[12]}; r11 = v2f{L[4], L[13]}; r12 = v2f{L[5], L[14]};
        r20 = v2f{L[6], L[15]}; r21 = v2f{L[7], L[16]}; r22 = v2f{L[8], L[17]};
    } else {
        // tail block: direct guarded scalar loads, identity padding
        #pragma unroll
        for (int q = 0; q < 2; ++q) {
            long long mi = waveBase + 2 * lane + q;
            if (mi < (long long)n) {
                const float* r = rot + mi * 9;
                r00[q]=r[0]; r01[q]=r[1]; r02[q]=r[2];
                r10[q]=r[3]; r11[q]=r[4]; r12[q]=r[5];
                r20[q]=r[6]; r21[q]=r[7]; r22[q]=r[8];
            } else {
                r00[q]=1.f; r01[q]=0.f; r02[q]=0.f;
                r10[q]=0.f; r11[q]=1.f; r12[q]=0.f;
                r20[q]=0.f; r21[q]=0.f; r22[q]=1.f;
            }
        }
    }

    // X = mat @ rot
    v2f x00 = m00*r00 + m01*r10 + m02*r20;
    v2f x01 = m00*r01 + m01*r11 + m02*r21;
    v2f x02 = m00*r02 + m01*r12 + m02*r22;
    v2f x10 = m10*r00 + m11*r10 + m12*r20;
    v2f x11 = m10*r01 + m11*r11 + m12*r21;
    v2f x12 = m10*r02 + m11*r12 + m12*r22;
    v2f x20 = m20*r00 + m21*r10 + m22*r20;
    v2f x21 = m20*r01 + m21*r11 + m22*r21;
    v2f x22 = m20*r02 + m21*r12 + m22*r22;

    polar_pair(x00,x01,x02,x10,x11,x12,x20,x21,x22);

    if (full) {
        // ---- direct register stores: lane owns 18 consecutive floats ----
        // (stride 72B per lane; all slots >=8B aligned; fire-and-forget)
        v4fa8* gdst = (v4fa8*)(out + waveBase * 9 + lane * 18);
        v4f a0 = {x00.x, x01.x, x02.x, x10.x};
        v4f a1 = {x11.x, x12.x, x20.x, x21.x};
        v4f a2 = {x22.x, x00.y, x01.y, x02.y};
        v4f a3 = {x10.y, x11.y, x12.y, x20.y};
        v2f a4 = {x21.y, x22.y};
        __builtin_nontemporal_store(a0, gdst + 0);
        __builtin_nontemporal_store(a1, gdst + 1);
        __builtin_nontemporal_store(a2, gdst + 2);
        __builtin_nontemporal_store(a3, gdst + 3);
        __builtin_nontemporal_store(a4, (v2fa8*)(gdst + 4));

        // logdet zeros: this wave's 128 entries, float2 per lane
        v2fa8* ld2 = (v2fa8*)(out + (long long)n * 9 + waveBase + 2 * lane);
        __builtin_nontemporal_store(v2f{0.f, 0.f}, ld2);
    } else {
        #pragma unroll
        for (int q = 0; q < 2; ++q) {
            long long mi = waveBase + 2 * lane + q;
            if (mi < (long long)n) {
                float* o = out + mi * 9;
                o[0]=x00[q]; o[1]=x01[q]; o[2]=x02[q];
                o[3]=x10[q]; o[4]=x11[q]; o[5]=x12[q];
                o[6]=x20[q]; o[7]=x21[q]; o[8]=x22[q];
                out[(long long)n * 9 + mi] = 0.0f;
            }
        }
    }
}

extern "C" void kernel_launch(void* const* d_in, const int* in_sizes, int n_in,
                              void* d_out, int out_size, void* d_ws, size_t ws_size,
                              hipStream_t stream) {
    const float* rot = (const float*)d_in[0];
    const float* mat = (const float*)d_in[1];
    float* out = (float*)d_out;

    int n = in_sizes[0] / 9;
    int block = 256;
    int grid = (n + 511) / 512;   // 512 matrices per block, 2 per thread
    polar3x3_wave_kernel<<<grid, block, 0, stream>>>(rot, mat, out, n);
}

// Round 7
// 42.837 us; speedup vs baseline: 3.1583x; 3.1583x over previous
//
#include <hip/hip_runtime.h>
#include <math.h>

// Batched 3x3 polar decomposition, wave-autonomous:
//  - each wave stages its own 128 matrices global->LDS via global_load_lds
//    (linear dest, 4x16B + 2x4B per lane), NO __syncthreads anywhere
//  - 2 matrices/thread packed into float2 vectors -> v_pk_fma_f32
//  - 6 det-scaled Newton iterations + 2 Newton-Schulz polish
//  - results stored DIRECTLY from registers as CACHED stores (stride-72B/lane;
//    every 64B line is fully written by the wave within 5 instructions, so L2
//    write-merges to full-line evictions -- exact HBM write volume).
//    R6 lesson: nontemporal bypasses L2 merge -> 3.4x write amplification on
//    scattered stores. nt kept ONLY for the line-contiguous logdet fill.

typedef float v2f __attribute__((ext_vector_type(2)));
typedef float v4f __attribute__((ext_vector_type(4)));
typedef v4f v4fa8 __attribute__((aligned(8)));   // 16B vector in 8B-aligned slot
typedef v2f v2fa8 __attribute__((aligned(8)));

#define NEWTON_ITERS 6
#define NS_ITERS 2

__device__ __forceinline__ void polar_pair(
    v2f& x00, v2f& x01, v2f& x02,
    v2f& x10, v2f& x11, v2f& x12,
    v2f& x20, v2f& x21, v2f& x22)
{
    #pragma unroll
    for (int it = 0; it < NEWTON_ITERS; ++it) {
        v2f c00 = x11*x22 - x12*x21;
        v2f c01 = x12*x20 - x10*x22;
        v2f c02 = x10*x21 - x11*x20;
        v2f c10 = x02*x21 - x01*x22;
        v2f c11 = x00*x22 - x02*x20;
        v2f c12 = x01*x20 - x00*x21;
        v2f c20 = x01*x12 - x02*x11;
        v2f c21 = x02*x10 - x00*x12;
        v2f c22 = x00*x11 - x01*x10;

        v2f det = x00*c00 + x01*c01 + x02*c02;

        float d0 = det.x, d1 = det.y;
        float ad0 = fmaxf(fabsf(d0), 1e-30f);
        float ad1 = fmaxf(fabsf(d1), 1e-30f);
        float z0 = __builtin_amdgcn_exp2f(__builtin_amdgcn_logf(ad0) * (-1.0f/3.0f));
        float z1 = __builtin_amdgcn_exp2f(__builtin_amdgcn_logf(ad1) * (-1.0f/3.0f));
        v2f s = {0.5f * z0, 0.5f * z1};
        v2f u = {copysignf(0.5f * z0 * z0, d0), copysignf(0.5f * z1 * z1, d1)};

        x00 = s*x00 + u*c00;  x01 = s*x01 + u*c01;  x02 = s*x02 + u*c02;
        x10 = s*x10 + u*c10;  x11 = s*x11 + u*c11;  x12 = s*x12 + u*c12;
        x20 = s*x20 + u*c20;  x21 = s*x21 + u*c21;  x22 = s*x22 + u*c22;
    }

    #pragma unroll
    for (int it = 0; it < NS_ITERS; ++it) {
        v2f s00 = x00*x00 + x10*x10 + x20*x20;
        v2f s01 = x00*x01 + x10*x11 + x20*x21;
        v2f s02 = x00*x02 + x10*x12 + x20*x22;
        v2f s11 = x01*x01 + x11*x11 + x21*x21;
        v2f s12 = x01*x02 + x11*x12 + x21*x22;
        v2f s22 = x02*x02 + x12*x12 + x22*x22;
        v2f t00 = 1.5f - 0.5f*s00, t01 = -0.5f*s01, t02 = -0.5f*s02;
        v2f t11 = 1.5f - 0.5f*s11, t12 = -0.5f*s12;
        v2f t22 = 1.5f - 0.5f*s22;
        v2f y00 = x00*t00 + x01*t01 + x02*t02;
        v2f y01 = x00*t01 + x01*t11 + x02*t12;
        v2f y02 = x00*t02 + x01*t12 + x02*t22;
        v2f y10 = x10*t00 + x11*t01 + x12*t02;
        v2f y11 = x10*t01 + x11*t11 + x12*t12;
        v2f y12 = x10*t02 + x11*t12 + x12*t22;
        v2f y20 = x20*t00 + x21*t01 + x22*t02;
        v2f y21 = x20*t01 + x21*t11 + x22*t12;
        v2f y22 = x20*t02 + x21*t12 + x22*t22;
        x00=y00; x01=y01; x02=y02;
        x10=y10; x11=y11; x12=y12;
        x20=y20; x21=y21; x22=y22;
    }
}

__global__ __launch_bounds__(256) void polar3x3_wave_kernel(
    const float* __restrict__ rot,   // [n,3,3]
    const float* __restrict__ mat,   // [3,3] broadcast
    float* __restrict__ out,         // [n,3,3] then logdet[n]
    int n)
{
    __shared__ float lds[4608];              // 4 waves * 1152 floats (input only)
    const int t    = threadIdx.x;
    const int lane = t & 63;
    const int w    = t >> 6;
    const long long blockBase = (long long)blockIdx.x * 512;  // matrices
    const long long waveBase  = blockBase + (long long)w * 128;
    float* wlds = lds + w * 1152;

    // uniform parameter (scalar loads, overlap with staging)
    const float m00 = mat[0], m01 = mat[1], m02 = mat[2];
    const float m10 = mat[3], m11 = mat[4], m12 = mat[5];
    const float m20 = mat[6], m21 = mat[7], m22 = mat[8];

    const bool full = (blockBase + 512 <= (long long)n);

    v2f r00, r01, r02, r10, r11, r12, r20, r21, r22;

    if (full) {
        // ---- wave-local staging: 1152 floats, linear, no barrier ----
        const float* gsrc = rot + waveBase * 9;
        #pragma unroll
        for (int k = 0; k < 4; ++k) {
            __builtin_amdgcn_global_load_lds(
                (const __attribute__((address_space(1))) void*)(gsrc + k * 256 + lane * 4),
                (__attribute__((address_space(3))) void*)(wlds + k * 256),
                16, 0, 0);
        }
        #pragma unroll
        for (int k = 0; k < 2; ++k) {
            __builtin_amdgcn_global_load_lds(
                (const __attribute__((address_space(1))) void*)(gsrc + 1024 + k * 64 + lane),
                (__attribute__((address_space(3))) void*)(wlds + 1024 + k * 64),
                4, 0, 0);
        }

        // logdet zeros: independent of staging -- fire before the wait.
        // per-instruction line-contiguous (512B/wave), nt safe here.
        v2fa8* ld2 = (v2fa8*)(out + (long long)n * 9 + waveBase + 2 * lane);
        __builtin_nontemporal_store(v2f{0.f, 0.f}, ld2);

        asm volatile("s_waitcnt vmcnt(0)" ::: "memory");

        const float* L = wlds + lane * 18;   // this lane's 2 matrices
        r00 = v2f{L[0], L[9]};  r01 = v2f{L[1], L[10]}; r02 = v2f{L[2], L[11]};
        r10 = v2f{L[3], L[12]}; r11 = v2f{L[4], L[13]}; r12 = v2f{L[5], L[14]};
        r20 = v2f{L[6], L[15]}; r21 = v2f{L[7], L[16]}; r22 = v2f{L[8], L[17]};
    } else {
        // tail block: direct guarded scalar loads, identity padding
        #pragma unroll
        for (int q = 0; q < 2; ++q) {
            long long mi = waveBase + 2 * lane + q;
            if (mi < (long long)n) {
                const float* r = rot + mi * 9;
                r00[q]=r[0]; r01[q]=r[1]; r02[q]=r[2];
                r10[q]=r[3]; r11[q]=r[4]; r12[q]=r[5];
                r20[q]=r[6]; r21[q]=r[7]; r22[q]=r[8];
            } else {
                r00[q]=1.f; r01[q]=0.f; r02[q]=0.f;
                r10[q]=0.f; r11[q]=1.f; r12[q]=0.f;
                r20[q]=0.f; r21[q]=0.f; r22[q]=1.f;
            }
        }
    }

    // X = mat @ rot
    v2f x00 = m00*r00 + m01*r10 + m02*r20;
    v2f x01 = m00*r01 + m01*r11 + m02*r21;
    v2f x02 = m00*r02 + m01*r12 + m02*r22;
    v2f x10 = m10*r00 + m11*r10 + m12*r20;
    v2f x11 = m10*r01 + m11*r11 + m12*r21;
    v2f x12 = m10*r02 + m11*r12 + m12*r22;
    v2f x20 = m20*r00 + m21*r10 + m22*r20;
    v2f x21 = m20*r01 + m21*r11 + m22*r21;
    v2f x22 = m20*r02 + m21*r12 + m22*r22;

    polar_pair(x00,x01,x02,x10,x11,x12,x20,x21,x22);

    if (full) {
        // ---- direct register stores, CACHED (L2 write-merges the lines) ----
        v4fa8* gdst = (v4fa8*)(out + waveBase * 9 + lane * 18);
        v4f a0 = {x00.x, x01.x, x02.x, x10.x};
        v4f a1 = {x11.x, x12.x, x20.x, x21.x};
        v4f a2 = {x22.x, x00.y, x01.y, x02.y};
        v4f a3 = {x10.y, x11.y, x12.y, x20.y};
        v2f a4 = {x21.y, x22.y};
        gdst[0] = a0;
        gdst[1] = a1;
        gdst[2] = a2;
        gdst[3] = a3;
        *(v2fa8*)(gdst + 4) = a4;
    } else {
        #pragma unroll
        for (int q = 0; q < 2; ++q) {
            long long mi = waveBase + 2 * lane + q;
            if (mi < (long long)n) {
                float* o = out + mi * 9;
                o[0]=x00[q]; o[1]=x01[q]; o[2]=x02[q];
                o[3]=x10[q]; o[4]=x11[q]; o[5]=x12[q];
                o[6]=x20[q]; o[7]=x21[q]; o[8]=x22[q];
                out[(long long)n * 9 + mi] = 0.0f;
            }
        }
    }
}

extern "C" void kernel_launch(void* const* d_in, const int* in_sizes, int n_in,
                              void* d_out, int out_size, void* d_ws, size_t ws_size,
                              hipStream_t stream) {
    const float* rot = (const float*)d_in[0];
    const float* mat = (const float*)d_in[1];
    float* out = (float*)d_out;

    int n = in_sizes[0] / 9;
    int block = 256;
    int grid = (n + 511) / 512;   // 512 matrices per block, 2 per thread
    polar3x3_wave_kernel<<<grid, block, 0, stream>>>(rot, mat, out, n);
}

// Round 8
// 32.267 us; speedup vs baseline: 4.1929x; 1.3276x over previous
//
#include <hip/hip_runtime.h>
#include <math.h>

// Batched 3x3 polar decomposition, wave-autonomous, 4 matrices/thread:
//  - each wave stages its own 256 matrices (2304 floats = 9 x 16B per lane)
//    global->LDS via global_load_lds, linear dest, NO __syncthreads anywhere
//  - per thread: TWO independent packed chains (v2f = 2 matrices each) so the
//    scheduler interleaves them and hides the Newton chain's ALU latency
//  - 6 det-scaled Newton iterations + 2 Newton-Schulz polish (proven math)
//  - output restaged in the wave's LDS region -> coalesced float4 stores
//    (R7 lesson: scattered per-lane stores cost ~64 L2 transactions/instr;
//     R6 lesson: nontemporal on scattered stores -> 3.4x write amplification.
//     nt kept ONLY for the line-contiguous logdet fill.)

typedef float v2f __attribute__((ext_vector_type(2)));
typedef float v4f __attribute__((ext_vector_type(4)));

#define NEWTON_ITERS 6
#define NS_ITERS 2

__device__ __forceinline__ void polar_pair(
    v2f& x00, v2f& x01, v2f& x02,
    v2f& x10, v2f& x11, v2f& x12,
    v2f& x20, v2f& x21, v2f& x22)
{
    #pragma unroll
    for (int it = 0; it < NEWTON_ITERS; ++it) {
        v2f c00 = x11*x22 - x12*x21;
        v2f c01 = x12*x20 - x10*x22;
        v2f c02 = x10*x21 - x11*x20;
        v2f c10 = x02*x21 - x01*x22;
        v2f c11 = x00*x22 - x02*x20;
        v2f c12 = x01*x20 - x00*x21;
        v2f c20 = x01*x12 - x02*x11;
        v2f c21 = x02*x10 - x00*x12;
        v2f c22 = x00*x11 - x01*x10;

        v2f det = x00*c00 + x01*c01 + x02*c02;

        float d0 = det.x, d1 = det.y;
        float ad0 = fmaxf(fabsf(d0), 1e-30f);
        float ad1 = fmaxf(fabsf(d1), 1e-30f);
        float z0 = __builtin_amdgcn_exp2f(__builtin_amdgcn_logf(ad0) * (-1.0f/3.0f));
        float z1 = __builtin_amdgcn_exp2f(__builtin_amdgcn_logf(ad1) * (-1.0f/3.0f));
        v2f s = {0.5f * z0, 0.5f * z1};
        v2f u = {copysignf(0.5f * z0 * z0, d0), copysignf(0.5f * z1 * z1, d1)};

        x00 = s*x00 + u*c00;  x01 = s*x01 + u*c01;  x02 = s*x02 + u*c02;
        x10 = s*x10 + u*c10;  x11 = s*x11 + u*c11;  x12 = s*x12 + u*c12;
        x20 = s*x20 + u*c20;  x21 = s*x21 + u*c21;  x22 = s*x22 + u*c22;
    }

    #pragma unroll
    for (int it = 0; it < NS_ITERS; ++it) {
        v2f s00 = x00*x00 + x10*x10 + x20*x20;
        v2f s01 = x00*x01 + x10*x11 + x20*x21;
        v2f s02 = x00*x02 + x10*x12 + x20*x22;
        v2f s11 = x01*x01 + x11*x11 + x21*x21;
        v2f s12 = x01*x02 + x11*x12 + x21*x22;
        v2f s22 = x02*x02 + x12*x12 + x22*x22;
        v2f t00 = 1.5f - 0.5f*s00, t01 = -0.5f*s01, t02 = -0.5f*s02;
        v2f t11 = 1.5f - 0.5f*s11, t12 = -0.5f*s12;
        v2f t22 = 1.5f - 0.5f*s22;
        v2f y00 = x00*t00 + x01*t01 + x02*t02;
        v2f y01 = x00*t01 + x01*t11 + x02*t12;
        v2f y02 = x00*t02 + x01*t12 + x02*t22;
        v2f y10 = x10*t00 + x11*t01 + x12*t02;
        v2f y11 = x10*t01 + x11*t11 + x12*t12;
        v2f y12 = x10*t02 + x11*t12 + x12*t22;
        v2f y20 = x20*t00 + x21*t01 + x22*t02;
        v2f y21 = x20*t01 + x21*t11 + x22*t12;
        v2f y22 = x20*t02 + x21*t12 + x22*t22;
        x00=y00; x01=y01; x02=y02;
        x10=y10; x11=y11; x12=y12;
        x20=y20; x21=y21; x22=y22;
    }
}

#define MATMUL_INIT(x, r)                                                     \
    x##00 = m00*r##00 + m01*r##10 + m02*r##20;                                \
    x##01 = m00*r##01 + m01*r##11 + m02*r##21;                                \
    x##02 = m00*r##02 + m01*r##12 + m02*r##22;                                \
    x##10 = m10*r##00 + m11*r##10 + m12*r##20;                                \
    x##11 = m10*r##01 + m11*r##11 + m12*r##21;                                \
    x##12 = m10*r##02 + m11*r##12 + m12*r##22;                                \
    x##20 = m20*r##00 + m21*r##10 + m22*r##20;                                \
    x##21 = m20*r##01 + m21*r##11 + m22*r##21;                                \
    x##22 = m20*r##02 + m21*r##12 + m22*r##22;

__global__ __launch_bounds__(128) void polar3x3_x4_kernel(
    const float* __restrict__ rot,   // [n,3,3]
    const float* __restrict__ mat,   // [3,3] broadcast
    float* __restrict__ out,         // [n,3,3] then logdet[n]
    int n)
{
    __shared__ __align__(16) float lds[4608];   // 2 waves * 2304 floats
    const int t    = threadIdx.x;
    const int lane = t & 63;
    const int w    = t >> 6;
    const long long blockBase = (long long)blockIdx.x * 512;   // matrices/block
    const long long waveBase  = blockBase + (long long)w * 256; // matrices/wave
    float* wlds = lds + w * 2304;

    const float m00 = mat[0], m01 = mat[1], m02 = mat[2];
    const float m10 = mat[3], m11 = mat[4], m12 = mat[5];
    const float m20 = mat[6], m21 = mat[7], m22 = mat[8];

    const bool full = (blockBase + 512 <= (long long)n);

    v2f a00,a01,a02,a10,a11,a12,a20,a21,a22;   // chain A: matrices waveBase+2*lane+{0,1}
    v2f b00,b01,b02,b10,b11,b12,b20,b21,b22;   // chain B: matrices waveBase+128+2*lane+{0,1}

    if (full) {
        // ---- wave-local staging: 2304 floats = 9 x 16B per lane, linear ----
        const float* gsrc = rot + waveBase * 9;
        #pragma unroll
        for (int k = 0; k < 9; ++k) {
            __builtin_amdgcn_global_load_lds(
                (const __attribute__((address_space(1))) void*)(gsrc + k * 256 + lane * 4),
                (__attribute__((address_space(3))) void*)(wlds + k * 256),
                16, 0, 0);
        }

        // logdet zeros (independent of staging; line-contiguous per instr -> nt safe)
        v4f* ld4 = (v4f*)(out + (long long)n * 9 + waveBase);
        __builtin_nontemporal_store(v4f{0.f, 0.f, 0.f, 0.f}, ld4 + lane);

        asm volatile("s_waitcnt vmcnt(0)" ::: "memory");

        // stride-18-word reads (2-way bank alias = free); chain B at +1152 words
        const float* LA = wlds + lane * 18;
        const float* LB = wlds + 1152 + lane * 18;
        a00 = v2f{LA[0], LA[9]};  a01 = v2f{LA[1], LA[10]}; a02 = v2f{LA[2], LA[11]};
        a10 = v2f{LA[3], LA[12]}; a11 = v2f{LA[4], LA[13]}; a12 = v2f{LA[5], LA[14]};
        a20 = v2f{LA[6], LA[15]}; a21 = v2f{LA[7], LA[16]}; a22 = v2f{LA[8], LA[17]};
        b00 = v2f{LB[0], LB[9]};  b01 = v2f{LB[1], LB[10]}; b02 = v2f{LB[2], LB[11]};
        b10 = v2f{LB[3], LB[12]}; b11 = v2f{LB[4], LB[13]}; b12 = v2f{LB[5], LB[14]};
        b20 = v2f{LB[6], LB[15]}; b21 = v2f{LB[7], LB[16]}; b22 = v2f{LB[8], LB[17]};
    } else {
        // tail block: guarded scalar loads, identity padding
        #pragma unroll
        for (int q = 0; q < 2; ++q) {
            long long miA = waveBase + 2 * lane + q;
            long long miB = waveBase + 128 + 2 * lane + q;
            if (miA < (long long)n) {
                const float* r = rot + miA * 9;
                a00[q]=r[0]; a01[q]=r[1]; a02[q]=r[2];
                a10[q]=r[3]; a11[q]=r[4]; a12[q]=r[5];
                a20[q]=r[6]; a21[q]=r[7]; a22[q]=r[8];
            } else {
                a00[q]=1.f; a01[q]=0.f; a02[q]=0.f;
                a10[q]=0.f; a11[q]=1.f; a12[q]=0.f;
                a20[q]=0.f; a21[q]=0.f; a22[q]=1.f;
            }
            if (miB < (long long)n) {
                const float* r = rot + miB * 9;
                b00[q]=r[0]; b01[q]=r[1]; b02[q]=r[2];
                b10[q]=r[3]; b11[q]=r[4]; b12[q]=r[5];
                b20[q]=r[6]; b21[q]=r[7]; b22[q]=r[8];
            } else {
                b00[q]=1.f; b01[q]=0.f; b02[q]=0.f;
                b10[q]=0.f; b11[q]=1.f; b12[q]=0.f;
                b20[q]=0.f; b21[q]=0.f; b22[q]=1.f;
            }
        }
    }

    // X = mat @ rot, then polar iteration -- two independent chains
    v2f xa00,xa01,xa02,xa10,xa11,xa12,xa20,xa21,xa22;
    v2f xb00,xb01,xb02,xb10,xb11,xb12,xb20,xb21,xb22;
    MATMUL_INIT(xa, a)
    MATMUL_INIT(xb, b)

    polar_pair(xa00,xa01,xa02,xa10,xa11,xa12,xa20,xa21,xa22);
    polar_pair(xb00,xb01,xb02,xb10,xb11,xb12,xb20,xb21,xb22);

    if (full) {
        // ---- restage results (same addresses this thread read; in-order DS) ----
        float* SA = wlds + lane * 18;
        float* SB = wlds + 1152 + lane * 18;
        SA[0]=xa00.x; SA[9] =xa00.y; SA[1]=xa01.x; SA[10]=xa01.y; SA[2]=xa02.x; SA[11]=xa02.y;
        SA[3]=xa10.x; SA[12]=xa10.y; SA[4]=xa11.x; SA[13]=xa11.y; SA[5]=xa12.x; SA[14]=xa12.y;
        SA[6]=xa20.x; SA[15]=xa20.y; SA[7]=xa21.x; SA[16]=xa21.y; SA[8]=xa22.x; SA[17]=xa22.y;
        SB[0]=xb00.x; SB[9] =xb00.y; SB[1]=xb01.x; SB[10]=xb01.y; SB[2]=xb02.x; SB[11]=xb02.y;
        SB[3]=xb10.x; SB[12]=xb10.y; SB[4]=xb11.x; SB[13]=xb11.y; SB[5]=xb12.x; SB[14]=xb12.y;
        SB[6]=xb20.x; SB[15]=xb20.y; SB[7]=xb21.x; SB[16]=xb21.y; SB[8]=xb22.x; SB[17]=xb22.y;

        // coalesced float4 stores: 576 float4 per wave = 9 per lane
        v4f* gdst4 = (v4f*)(out + waveBase * 9);
        const v4f* l4 = (const v4f*)wlds;
        #pragma unroll
        for (int k = 0; k < 9; ++k)
            gdst4[k * 64 + lane] = l4[k * 64 + lane];
    } else {
        #pragma unroll
        for (int q = 0; q < 2; ++q) {
            long long miA = waveBase + 2 * lane + q;
            long long miB = waveBase + 128 + 2 * lane + q;
            if (miA < (long long)n) {
                float* o = out + miA * 9;
                o[0]=xa00[q]; o[1]=xa01[q]; o[2]=xa02[q];
                o[3]=xa10[q]; o[4]=xa11[q]; o[5]=xa12[q];
                o[6]=xa20[q]; o[7]=xa21[q]; o[8]=xa22[q];
                out[(long long)n * 9 + miA] = 0.0f;
            }
            if (miB < (long long)n) {
                float* o = out + miB * 9;
                o[0]=xb00[q]; o[1]=xb01[q]; o[2]=xb02[q];
                o[3]=xb10[q]; o[4]=xb11[q]; o[5]=xb12[q];
                o[6]=xb20[q]; o[7]=xb21[q]; o[8]=xb22[q];
                out[(long long)n * 9 + miB] = 0.0f;
            }
        }
    }
}

extern "C" void kernel_launch(void* const* d_in, const int* in_sizes, int n_in,
                              void* d_out, int out_size, void* d_ws, size_t ws_size,
                              hipStream_t stream) {
    const float* rot = (const float*)d_in[0];
    const float* mat = (const float*)d_in[1];
    float* out = (float*)d_out;

    int n = in_sizes[0] / 9;
    int block = 128;                  // 2 waves; each wave owns 256 matrices
    int grid = (n + 511) / 512;       // 512 matrices per block
    polar3x3_x4_kernel<<<grid, block, 0, stream>>>(rot, mat, out, n);
}

// Round 9
// 30.608 us; speedup vs baseline: 4.4202x; 1.0542x over previous
//
#include <hip/hip_runtime.h>
#include <math.h>

// Batched 3x3 polar decomposition, wave-autonomous, software-pipelined:
//  - each wave owns 256 matrices = 2 tiles x 128, double-buffered LDS
//  - issue buf0 loads, buf1 loads, then COUNTED s_waitcnt vmcnt(6): compute
//    tile0 while tile1's loads stay in flight (T4 pattern); second vmcnt(6)
//    finds tile1 already resident (latency hidden under tile0 compute).
//  - 2 matrices/thread packed into v2f -> v_pk_fma_f32; 6 det-scaled Newton
//    + 2 Newton-Schulz polish (proven math, absmax 0.0039)
//  - output restaged through the wave's LDS buffer -> coalesced v4f stores
//    (R6: nt on scattered stores -> 3.4x write amplification;
//     R7: cached scattered stores -> ~64 L2 transactions/instr;
//     nt kept ONLY for the line-contiguous logdet fill.)

typedef float v2f __attribute__((ext_vector_type(2)));
typedef float v4f __attribute__((ext_vector_type(4)));

#define NEWTON_ITERS 6
#define NS_ITERS 2

__device__ __forceinline__ void polar_pair(
    v2f& x00, v2f& x01, v2f& x02,
    v2f& x10, v2f& x11, v2f& x12,
    v2f& x20, v2f& x21, v2f& x22)
{
    #pragma unroll
    for (int it = 0; it < NEWTON_ITERS; ++it) {
        v2f c00 = x11*x22 - x12*x21;
        v2f c01 = x12*x20 - x10*x22;
        v2f c02 = x10*x21 - x11*x20;
        v2f c10 = x02*x21 - x01*x22;
        v2f c11 = x00*x22 - x02*x20;
        v2f c12 = x01*x20 - x00*x21;
        v2f c20 = x01*x12 - x02*x11;
        v2f c21 = x02*x10 - x00*x12;
        v2f c22 = x00*x11 - x01*x10;

        v2f det = x00*c00 + x01*c01 + x02*c02;

        float d0 = det.x, d1 = det.y;
        float ad0 = fmaxf(fabsf(d0), 1e-30f);
        float ad1 = fmaxf(fabsf(d1), 1e-30f);
        float z0 = __builtin_amdgcn_exp2f(__builtin_amdgcn_logf(ad0) * (-1.0f/3.0f));
        float z1 = __builtin_amdgcn_exp2f(__builtin_amdgcn_logf(ad1) * (-1.0f/3.0f));
        v2f s = {0.5f * z0, 0.5f * z1};
        v2f u = {copysignf(0.5f * z0 * z0, d0), copysignf(0.5f * z1 * z1, d1)};

        x00 = s*x00 + u*c00;  x01 = s*x01 + u*c01;  x02 = s*x02 + u*c02;
        x10 = s*x10 + u*c10;  x11 = s*x11 + u*c11;  x12 = s*x12 + u*c12;
        x20 = s*x20 + u*c20;  x21 = s*x21 + u*c21;  x22 = s*x22 + u*c22;
    }

    #pragma unroll
    for (int it = 0; it < NS_ITERS; ++it) {
        v2f s00 = x00*x00 + x10*x10 + x20*x20;
        v2f s01 = x00*x01 + x10*x11 + x20*x21;
        v2f s02 = x00*x02 + x10*x12 + x20*x22;
        v2f s11 = x01*x01 + x11*x11 + x21*x21;
        v2f s12 = x01*x02 + x11*x12 + x21*x22;
        v2f s22 = x02*x02 + x12*x12 + x22*x22;
        v2f t00 = 1.5f - 0.5f*s00, t01 = -0.5f*s01, t02 = -0.5f*s02;
        v2f t11 = 1.5f - 0.5f*s11, t12 = -0.5f*s12;
        v2f t22 = 1.5f - 0.5f*s22;
        v2f y00 = x00*t00 + x01*t01 + x02*t02;
        v2f y01 = x00*t01 + x01*t11 + x02*t12;
        v2f y02 = x00*t02 + x01*t12 + x02*t22;
        v2f y10 = x10*t00 + x11*t01 + x12*t02;
        v2f y11 = x10*t01 + x11*t11 + x12*t12;
        v2f y12 = x10*t02 + x11*t12 + x12*t22;
        v2f y20 = x20*t00 + x21*t01 + x22*t02;
        v2f y21 = x20*t01 + x21*t11 + x22*t12;
        v2f y22 = x20*t02 + x21*t12 + x22*t22;
        x00=y00; x01=y01; x02=y02;
        x10=y10; x11=y11; x12=y12;
        x20=y20; x21=y21; x22=y22;
    }
}

// compute one 128-matrix tile from LDS buffer `buf`, restage into `buf`,
// store coalesced to out+tileBase*9
__device__ __forceinline__ void compute_tile(
    float* buf, int lane, float* outBase,
    float m00, float m01, float m02,
    float m10, float m11, float m12,
    float m20, float m21, float m22)
{
    const float* L = buf + lane * 18;
    v2f r00 = {L[0], L[9]},  r01 = {L[1], L[10]}, r02 = {L[2], L[11]};
    v2f r10 = {L[3], L[12]}, r11 = {L[4], L[13]}, r12 = {L[5], L[14]};
    v2f r20 = {L[6], L[15]}, r21 = {L[7], L[16]}, r22 = {L[8], L[17]};

    v2f x00 = m00*r00 + m01*r10 + m02*r20;
    v2f x01 = m00*r01 + m01*r11 + m02*r21;
    v2f x02 = m00*r02 + m01*r12 + m02*r22;
    v2f x10 = m10*r00 + m11*r10 + m12*r20;
    v2f x11 = m10*r01 + m11*r11 + m12*r21;
    v2f x12 = m10*r02 + m11*r12 + m12*r22;
    v2f x20 = m20*r00 + m21*r10 + m22*r20;
    v2f x21 = m20*r01 + m21*r11 + m22*r21;
    v2f x22 = m20*r02 + m21*r12 + m22*r22;

    polar_pair(x00,x01,x02,x10,x11,x12,x20,x21,x22);

    float* S = buf + lane * 18;
    S[0]=x00.x; S[9] =x00.y; S[1]=x01.x; S[10]=x01.y; S[2]=x02.x; S[11]=x02.y;
    S[3]=x10.x; S[12]=x10.y; S[4]=x11.x; S[13]=x11.y; S[5]=x12.x; S[14]=x12.y;
    S[6]=x20.x; S[15]=x20.y; S[7]=x21.x; S[16]=x21.y; S[8]=x22.x; S[17]=x22.y;

    // coalesced stores: 1152 floats = 4 v4f + 1 v2f per lane
    v4f* g4 = (v4f*)outBase;
    const v4f* l4 = (const v4f*)buf;
    #pragma unroll
    for (int k = 0; k < 4; ++k)
        g4[k * 64 + lane] = l4[k * 64 + lane];
    ((v2f*)(outBase + 1024))[lane] = ((const v2f*)(buf + 1024))[lane];
}

__device__ __forceinline__ void stage_tile(const float* gsrc, float* buf, int lane)
{
    #pragma unroll
    for (int k = 0; k < 4; ++k) {
        __builtin_amdgcn_global_load_lds(
            (const __attribute__((address_space(1))) void*)(gsrc + k * 256 + lane * 4),
            (__attribute__((address_space(3))) void*)(buf + k * 256),
            16, 0, 0);
    }
    #pragma unroll
    for (int k = 0; k < 2; ++k) {
        __builtin_amdgcn_global_load_lds(
            (const __attribute__((address_space(1))) void*)(gsrc + 1024 + k * 64 + lane),
            (__attribute__((address_space(3))) void*)(buf + 1024 + k * 64),
            4, 0, 0);
    }
}

__global__ __launch_bounds__(256) void polar3x3_pipe_kernel(
    const float* __restrict__ rot,   // [n,3,3]
    const float* __restrict__ mat,   // [3,3] broadcast
    float* __restrict__ out,         // [n,3,3] then logdet[n]
    int n)
{
    __shared__ __align__(16) float lds[9216];   // 4 waves * 2 bufs * 1152
    const int t    = threadIdx.x;
    const int lane = t & 63;
    const int w    = t >> 6;
    const long long blockBase = (long long)blockIdx.x * 1024;   // matrices/block
    const long long waveBase  = blockBase + (long long)w * 256; // 2 tiles of 128
    float* buf0 = lds + w * 2304;
    float* buf1 = buf0 + 1152;

    const float m00 = mat[0], m01 = mat[1], m02 = mat[2];
    const float m10 = mat[3], m11 = mat[4], m12 = mat[5];
    const float m20 = mat[6], m21 = mat[7], m22 = mat[8];

    const bool full = (blockBase + 1024 <= (long long)n);

    if (full) {
        // issue both tiles' staging back-to-back (12 loads in flight)
        stage_tile(rot + waveBase * 9, buf0, lane);
        stage_tile(rot + (waveBase + 128) * 9, buf1, lane);

        // tile0 ready when only tile1's 6 loads remain
        asm volatile("s_waitcnt vmcnt(6)" ::: "memory");

        // logdet zeros: 256/wave = 1 v4f per lane, line-contiguous -> nt safe
        v4f* ld4 = (v4f*)(out + (long long)n * 9 + waveBase);
        __builtin_nontemporal_store(v4f{0.f, 0.f, 0.f, 0.f}, ld4 + lane);

        compute_tile(buf0, lane, out + waveBase * 9,
                     m00,m01,m02,m10,m11,m12,m20,m21,m22);

        // tile1's 6 loads are the OLDEST outstanding ops (nt + 5 stores are
        // newer): <=6 outstanding guarantees tile1 resident
        asm volatile("s_waitcnt vmcnt(6)" ::: "memory");

        compute_tile(buf1, lane, out + (waveBase + 128) * 9,
                     m00,m01,m02,m10,m11,m12,m20,m21,m22);
    } else {
        // tail: guarded scalar path per tile (n = 2^21 -> never taken at this
        // size, kept for correctness at any n)
        #pragma unroll
        for (int tile = 0; tile < 2; ++tile) {
            long long tileBase = waveBase + tile * 128;
            v2f r00,r01,r02,r10,r11,r12,r20,r21,r22;
            #pragma unroll
            for (int q = 0; q < 2; ++q) {
                long long mi = tileBase + 2 * lane + q;
                if (mi < (long long)n) {
                    const float* r = rot + mi * 9;
                    r00[q]=r[0]; r01[q]=r[1]; r02[q]=r[2];
                    r10[q]=r[3]; r11[q]=r[4]; r12[q]=r[5];
                    r20[q]=r[6]; r21[q]=r[7]; r22[q]=r[8];
                } else {
                    r00[q]=1.f; r01[q]=0.f; r02[q]=0.f;
                    r10[q]=0.f; r11[q]=1.f; r12[q]=0.f;
                    r20[q]=0.f; r21[q]=0.f; r22[q]=1.f;
                }
            }
            v2f x00 = m00*r00 + m01*r10 + m02*r20;
            v2f x01 = m00*r01 + m01*r11 + m02*r21;
            v2f x02 = m00*r02 + m01*r12 + m02*r22;
            v2f x10 = m10*r00 + m11*r10 + m12*r20;
            v2f x11 = m10*r01 + m11*r11 + m12*r21;
            v2f x12 = m10*r02 + m11*r12 + m12*r22;
            v2f x20 = m20*r00 + m21*r10 + m22*r20;
            v2f x21 = m20*r01 + m21*r11 + m22*r21;
            v2f x22 = m20*r02 + m21*r12 + m22*r22;
            polar_pair(x00,x01,x02,x10,x11,x12,x20,x21,x22);
            #pragma unroll
            for (int q = 0; q < 2; ++q) {
                long long mi = tileBase + 2 * lane + q;
                if (mi < (long long)n) {
                    float* o = out + mi * 9;
                    o[0]=x00[q]; o[1]=x01[q]; o[2]=x02[q];
                    o[3]=x10[q]; o[4]=x11[q]; o[5]=x12[q];
                    o[6]=x20[q]; o[7]=x21[q]; o[8]=x22[q];
                    out[(long long)n * 9 + mi] = 0.0f;
                }
            }
        }
    }
}

extern "C" void kernel_launch(void* const* d_in, const int* in_sizes, int n_in,
                              void* d_out, int out_size, void* d_ws, size_t ws_size,
                              hipStream_t stream) {
    const float* rot = (const float*)d_in[0];
    const float* mat = (const float*)d_in[1];
    float* out = (float*)d_out;

    int n = in_sizes[0] / 9;
    int block = 256;                   // 4 waves; each wave owns 256 matrices
    int grid = (n + 1023) / 1024;      // 1024 matrices per block
    polar3x3_pipe_kernel<<<grid, block, 0, stream>>>(rot, mat, out, n);
}